// Round 10
// baseline (2371.370 us; speedup 1.0000x reference)
//
#include <hip/hip_runtime.h>
#include <stdint.h>

// Problem dims
#define Tn 512
#define Bn 128
#define NTOK (Bn*Tn)     // 65536
#define En 300
#define Hn 300
#define On 9
#define LDK 328          // LDS row stride in shorts (656 B rows, 16B-aligned)
#define HS 60            // hidden units per slice
#define NSL 5            // slices per direction (5*60 = 300)
#define NCH 8            // batch chunks
#define MC 16            // batch rows per chunk (one m-tile)
#define NBLK (2*NCH*NSL) // 80 blocks
#define NTHR 960         // 15 waves = 1 m-tile x 15 n-tiles; == MC*HS cell threads

// g_hx layout (R10): [dir][slot][unit 0..299][row 0..127], row stride 1,
// unit stride Bn. Each (unit, chunk) = exactly one 64B line (16 dwords,
// b0 % 16 == 0): a producing wave writes 4 such lines FULLY (4 units x 16
// consecutive rows), consumers poll full lines. R8/R9 lesson: the row-major
// layout made post-transpose publishes scatter 16B into 16 lines -> ~4x
// write amplification (WRITE_SIZE 307->641 MB).
#define HXSLOT (Hn*Bn)   // dwords per parity slot (38400)
#define HXDIR (2*HXSLOT) // dwords per direction

typedef short s4v __attribute__((ext_vector_type(4)));
typedef short s8v __attribute__((ext_vector_type(8)));
typedef float f4v __attribute__((ext_vector_type(4)));

// ---- static device scratch (d_ws unused) ----
__device__ unsigned short g_hcat[NTOK * 2 * Hn];   // 78,643,200 B — h outputs
// Tagged h-exchange packets, DWORD: (bf16(h) << 16) | produced_step.
// The data IS the flag: one atomic dword publishes value+validity.
// Publishes MUST stay agent-scope atomics (partial-line plain stores in
// non-coherent XCD L2s would false-share on full-line writeback).
__device__ unsigned int   g_hx[2 * HXDIR];         // 614,400 B

__device__ inline float b2f(unsigned short u){ unsigned v = ((unsigned)u) << 16; float f; __builtin_memcpy(&f, &v, 4); return f; }
__device__ inline unsigned short f2b(float f){ unsigned u; __builtin_memcpy(&u, &f, 4); u = u + 0x7fffu + ((u >> 16) & 1u); return (unsigned short)(u >> 16); }
__device__ inline float sigf(float x){ return 1.f / (1.f + __expf(-x)); }
__device__ inline float tanh_f(float x){ return 2.f / (1.f + __expf(-2.f * x)) - 1.f; }

// LDS-only barrier: drains lgkmcnt but NOT vmcnt, so in-flight global stores
// (the fire-and-forget h/hcat publishes) never sit on the critical path.
__device__ inline void bar_lgkm(){ asm volatile("s_waitcnt lgkmcnt(0)\n\ts_barrier" ::: "memory"); }

// ---------------- K0: init h-exchange tags to 0xFFFF (never matches a real step) ----------------
__global__ __launch_bounds__(256) void k_zero()
{
    const int i = blockIdx.x * 256 + threadIdx.x;
    const int stride = gridDim.x * 256;
    for (int j = i; j < 2 * HXDIR; j += stride) g_hx[j] = 0xFFFFu;
}

// ---------------- K1: fused bidirectional LSTM recurrence ----------------
// R10 = R9 with ONE change: g_hx transposed to [unit][row] so the in-wave-
// transpose cell's publishes are line-coalesced (see layout comment above).
// Publish path stays: MFMA2 -> 8x shfl 4x4 transpose -> cell -> publish
// (no Gsm, no barC). Protocol: R4's dword tagged packets, agent scope.
__global__ __launch_bounds__(NTHR, 4) void k_lstm(
    const int* __restrict__ x, const float* __restrict__ emb,
    const float* __restrict__ W_ih_f, const float* __restrict__ W_hh_f, const float* __restrict__ b_f,
    const float* __restrict__ W_ih_b, const float* __restrict__ W_hh_b, const float* __restrict__ b_b)
{
    const int bi    = blockIdx.x;
    const int dir   = bi / (NCH * NSL);
    const int rem   = bi % (NCH * NSL);
    const int chunk = rem / NSL;
    const int slice = rem % NSL;
    const int j0    = slice * HS;
    const int b0    = chunk * MC;

    const float* Wih  = dir ? W_ih_b : W_ih_f;
    const float* Whh  = dir ? W_hh_b : W_hh_f;
    const float* bias = dir ? b_b    : b_f;
    unsigned int* hxd = g_hx + (size_t)dir * HXDIR;

    __shared__ __align__(16) unsigned short Aemb[2][MC * LDK]; // 21 KB emb staging, double-buffered
    __shared__ __align__(16) unsigned short Hb[MC * LDK];      // 10.5 KB h staging
    __shared__ unsigned short Xl[MC * Tn];                     // 16 KB token ids (vocab<65536)

    const int tid  = threadIdx.x;
    const int lane = tid & 63;
    const int wid  = tid >> 6;              // 15 waves
    const int n0   = wid * 16;              // 15 n-tiles (240 gate cols); single m-tile
    const int kq   = (lane >> 4) * 8;       // k-subgroup within 32

    // ---- preload weight B-fragments (fp32 -> bf16 once, weight-stationary) ----
    // GATE-INTERLEAVED local col layout: nloc = 4*unit + gate (unit 0..59)
    const int nloc = n0 + (lane & 15);      // 0..239
    const int gq   = nloc & 3;              // gate index 0..3 (i,f,g,o)
    const int uq   = nloc >> 2;             // unit within slice 0..59
    const int grow = gq * Hn + j0 + uq;     // global row in [1200]
    s8v bih[10], bhh[10];
#pragma unroll
    for (int kc = 0; kc < 10; kc++) {
        int kb = kc * 32 + kq;
        s8v fi = {0,0,0,0,0,0,0,0}, fh = {0,0,0,0,0,0,0,0};
#pragma unroll
        for (int j = 0; j < 8; j++) {
            int k = kb + j;
            if (k < En) {
                fi[j] = (short)f2b(Wih[grow * En + k]);
                fh[j] = (short)f2b(Whh[grow * Hn + k]);
            }
        }
        bih[kc] = fi; bhh[kc] = fh;
    }

    // ---- per-LANE cell assignment (from the C-fragment layout + 4x4 transpose):
    // lane owns cell (batch row crow, unit cj); every lane of every wave active.
    const int crow = 4 * (lane >> 4) + (lane & 3);  // 0..15
    const int cu   = (lane >> 2) & 3;               // unit-in-wave 0..3
    const int cj   = j0 + 4 * wid + cu;             // unit within direction
    const float bi_i = bias[0 * Hn + cj];
    const float bi_f = bias[1 * Hn + cj];
    const float bi_g = bias[2 * Hn + cj];
    const float bi_o = bias[3 * Hn + cj];
    float creg = 0.f;
    const bool pub = ((cu & 1) == 0);               // even units pack hcat/LDS pairs (cj, cj+1)

    // ---- P3 assignment: 4 dword packets per thread over the OTHER 4 slices.
    // Unit-major / row-minor: consecutive lanes read consecutive rows of one
    // unit -> a wave polls 4 FULL 64B lines. (240 units x 16 rows = 4*NTHR.)
    int goffA[4], loffA[4];
#pragma unroll
    for (int j = 0; j < 4; j++) {
        int i  = tid + j * NTHR;            // 0..3839
        int c2 = i >> 4;                    // other-unit index 0..239
        int r  = i & 15;                    // row 0..15
        int c  = (c2 < j0) ? c2 : (c2 + HS);// skip own slice's 60 units
        goffA[j] = c * Bn + b0 + r;
        loffA[j] = r * LDK + c;
    }

    // ---- prologue: stage emb(s=0) into Aemb[0]; stage token ids; zero Hb pad ----
    {
        const int t0 = dir ? (Tn - 1) : 0;
        for (int i = tid; i < MC * 80; i += NTHR) {
            int r = i / 80, c = i - r * 80;
            s4v v = {0, 0, 0, 0};
            if (c < 75) {
                int xi = x[(b0 + r) * Tn + t0];
                float4 f = *(const float4*)(emb + (size_t)xi * En + c * 4);
                v[0] = (short)f2b(f.x); v[1] = (short)f2b(f.y);
                v[2] = (short)f2b(f.z); v[3] = (short)f2b(f.w);
            }
            *(s4v*)&Aemb[0][r * LDK + c * 4] = v;
        }
        for (int i = tid; i < MC * Tn; i += NTHR) {
            int r = i >> 9, tt = i & (Tn - 1);
            Xl[i] = (unsigned short)x[(b0 + r) * Tn + tt];  // Xl[r*512 + t]
        }
        // MFMA2 reads shorts [0,320) per row; only [0,300) is ever filled. Zero
        // the pad once (garbage could be NaN; NaN*0 = NaN poisons the MFMA).
        if (tid < MC * 20) {
            int r = tid / 20, c = 300 + (tid % 20);
            Hb[r * LDK + c] = 0;
        }
        __syncthreads();
    }

#pragma unroll 1
    for (int s = 0; s < Tn; s++) {
        const int t   = dir ? (Tn - 1 - s) : s;
        const int cur = s & 1, nxt = cur ^ 1;

        // MFMA1: input projection part from Aemb[cur] (runs during the wait window)
        f4v acc = {0.f, 0.f, 0.f, 0.f};
        {
            const unsigned short* abase = &Aemb[cur][(lane & 15) * LDK + kq];
#pragma unroll
            for (int kc = 0; kc < 10; kc++) {
                s8v a = *(const s8v*)(abase + kc * 32);
                acc = __builtin_amdgcn_mfma_f32_16x16x32_bf16(a, bih[kc], acc, 0, 0, 0);
            }
        }

        if (s) {
            // P3: 4 unconditional dword atomic polls (straight-line, batched
            // behind one waitcnt). Reload-all retry is safe by the parity-slot
            // induction (satisfied packets can't change until WE publish s).
            const unsigned tgt = (unsigned)(s - 1);
            const unsigned int* hsrc = hxd + (size_t)(s & 1) * HXSLOT;
            unsigned int pv0, pv1, pv2, pv3;
            for (;;) {
                pv0 = __hip_atomic_load(hsrc + goffA[0], __ATOMIC_RELAXED, __HIP_MEMORY_SCOPE_AGENT);
                pv1 = __hip_atomic_load(hsrc + goffA[1], __ATOMIC_RELAXED, __HIP_MEMORY_SCOPE_AGENT);
                pv2 = __hip_atomic_load(hsrc + goffA[2], __ATOMIC_RELAXED, __HIP_MEMORY_SCOPE_AGENT);
                pv3 = __hip_atomic_load(hsrc + goffA[3], __ATOMIC_RELAXED, __HIP_MEMORY_SCOPE_AGENT);
                unsigned bad = ((pv0 ^ tgt) | (pv1 ^ tgt) | (pv2 ^ tgt) | (pv3 ^ tgt)) & 0xffffu;
                if (!bad) break;
            }
            Hb[loffA[0]] = (unsigned short)(pv0 >> 16);
            Hb[loffA[1]] = (unsigned short)(pv1 >> 16);
            Hb[loffA[2]] = (unsigned short)(pv2 >> 16);
            Hb[loffA[3]] = (unsigned short)(pv3 >> 16);
        }

        // emb prefetch for s+1 (token ids from LDS): issued after the poll so it
        // never sits ahead of poll loads in the in-order vmcnt queue; its HBM
        // latency hides under MFMA2 + cell.
        float4 pf[2];
        const bool do_pf = (s + 1 < Tn);
        if (do_pf) {
            const int tn1 = dir ? (Tn - 2 - s) : (s + 1);
#pragma unroll
            for (int k = 0; k < 2; k++) {
                int i = tid + k * NTHR;            // < 1920; valid when < 1280 = MC*80
                if (i < MC * 80) {
                    int r = i / 80, c = i - r * 80;
                    if (c < 75) {
                        int xi = (int)Xl[(r << 9) + tn1];
                        pf[k] = *(const float4*)(emb + (size_t)xi * En + c * 4);
                    }
                }
            }
        }

        if (s) {
            bar_lgkm();   // bar B: Hb ready (LDS only — no vmcnt drain)

            // MFMA2: recurrent part from Hb
            const unsigned short* abase = &Hb[(lane & 15) * LDK + kq];
#pragma unroll
            for (int kc = 0; kc < 10; kc++) {
                s8v a = *(const s8v*)(abase + kc * 32);
                acc = __builtin_amdgcn_mfma_f32_16x16x32_bf16(a, bhh[kc], acc, 0, 0, 0);
            }
        }
        // s == 0: h_0 == 0, recurrent term is zero — skip P3/MFMA2 entirely.

        // ---- in-wave 4x4 transpose within each 4-lane group (quad-perm shfls):
        // lane p of each quad ends with all 4 gates of batch row rbase+p.
        // HW-verified in R8/R9 (absmax unchanged).
        float vi, vf2, vg, vo;
        {
            const bool q0 = (lane & 1) != 0;
            const bool q1 = (lane & 2) != 0;
            float a0 = acc[0], a1 = acc[1], a2 = acc[2], a3 = acc[3];
            float s0 = __shfl_xor(a1, 1), s1 = __shfl_xor(a0, 1);
            float s2 = __shfl_xor(a3, 1), s3 = __shfl_xor(a2, 1);
            float b0v = q0 ? s0 : a0;
            float b1v = q0 ? a1 : s1;
            float b2v = q0 ? s2 : a2;
            float b3v = q0 ? a3 : s3;
            s0 = __shfl_xor(b2v, 2); s1 = __shfl_xor(b3v, 2);
            s2 = __shfl_xor(b0v, 2); s3 = __shfl_xor(b1v, 2);
            vi  = q1 ? s0 : b0v;
            vf2 = q1 ? s1 : b1v;
            vg  = q1 ? b2v : s2;
            vo  = q1 ? b3v : s3;
        }

        // elementwise LSTM cell + publishes (no LDS round trip, no barrier)
        {
            float gi  = vi  + bi_i;
            float gf  = vf2 + bi_f;
            float gg2 = vg  + bi_g;
            float go  = vo  + bi_o;
            float ivv = sigf(gi), fv = sigf(gf), gv = tanh_f(gg2), ov = sigf(go);
            creg = fv * creg + ivv * gv;
            float h = ov * tanh_f(creg);
            unsigned hb16 = (unsigned)f2b(h);

            // tagged dword packet, [unit][row] layout: wave writes 4 FULL lines
            __hip_atomic_store(hxd + (size_t)((s + 1) & 1) * HXSLOT + cj * Bn + b0 + crow,
                               (hb16 << 16) | (unsigned)s,
                               __ATOMIC_RELAXED, __HIP_MEMORY_SCOPE_AGENT);

            float hn = __shfl_down(h, 4);          // partner unit cj+1 (lane+4, same row)
            if (pub) {
                unsigned pkt = hb16 | ((unsigned)f2b(hn) << 16);
                // own-slice h for step s+1 via LDS (bar D orders it)
                ((unsigned int*)Hb)[(crow * LDK + cj) >> 1] = pkt;
                // hcat output (fire-and-forget; same span pattern as R4)
                __hip_atomic_store((unsigned int*)g_hcat
                                       + (((size_t)((b0 + crow) * Tn + t)) * (2 * Hn) + dir * Hn + cj) / 2,
                                   pkt, __ATOMIC_RELAXED, __HIP_MEMORY_SCOPE_AGENT);
            }
        }

        // writeback prefetched emb(s+1) -> Aemb[nxt] (covered by bar D)
        if (do_pf) {
#pragma unroll
            for (int k = 0; k < 2; k++) {
                int i = tid + k * NTHR;
                if (i < MC * 80) {
                    int r = i / 80, c = i - r * 80;
                    s4v v = {0, 0, 0, 0};
                    if (c < 75) {
                        v[0] = (short)f2b(pf[k].x); v[1] = (short)f2b(pf[k].y);
                        v[2] = (short)f2b(pf[k].z); v[3] = (short)f2b(pf[k].w);
                    }
                    *(s4v*)&Aemb[nxt][r * LDK + c * 4] = v;
                }
            }
        }
        bar_lgkm();   // bar D: Aemb[nxt] + Hb self-writes visible (LDS only)
    }
}

// ---------------- K2: fused out-projection + softmax, one wave per 16 positions ----------------
__global__ __launch_bounds__(256) void k_out(
    const float* __restrict__ W_lin, const float* __restrict__ b_lin, float* __restrict__ out)
{
    __shared__ float Wl[On * 2 * Hn];  // 21.6 KB
    __shared__ float bl[On];
    const int tid = threadIdx.x;
    for (int i = tid; i < On * 2 * Hn; i += 256) Wl[i] = W_lin[i];
    if (tid < On) bl[tid] = b_lin[tid];
    __syncthreads();

    const int lane = tid & 63;
    const int w    = tid >> 6;
    const int wg   = blockIdx.x * 4 + w;      // 4096 waves
    for (int it = 0; it < 16; it++) {
        const int p = wg * 16 + it;           // 0..65535
        const unsigned int* rowd = (const unsigned int*)(g_hcat + (size_t)p * (2 * Hn)); // 300 dwords
        float part[On];
#pragma unroll
        for (int o = 0; o < On; o++) part[o] = 0.f;
#pragma unroll
        for (int c = 0; c < 5; c++) {
            int k = lane + 64 * c;            // dword index, 2 shorts each
            if (k < Hn) {
                unsigned v2 = rowd[k];
                float vlo = b2f((unsigned short)(v2 & 0xffffu));
                float vhi = b2f((unsigned short)(v2 >> 16));
#pragma unroll
                for (int o = 0; o < On; o++)
                    part[o] += vlo * Wl[o * (2 * Hn) + 2 * k] + vhi * Wl[o * (2 * Hn) + 2 * k + 1];
            }
        }
#pragma unroll
        for (int off = 32; off >= 1; off >>= 1) {
#pragma unroll
            for (int o = 0; o < On; o++) part[o] += __shfl_xor(part[o], off, 64);
        }
        if (lane == 0) {
            float lg[On];
            float m = -1e30f;
#pragma unroll
            for (int o = 0; o < On; o++) { lg[o] = part[o] + bl[o]; m = fmaxf(m, lg[o]); }
            float ssum = 0.f;
#pragma unroll
            for (int o = 0; o < On; o++) { lg[o] = __expf(lg[o] - m); ssum += lg[o]; }
            float inv = 1.f / ssum;
#pragma unroll
            for (int o = 0; o < On; o++) out[(size_t)p * On + o] = lg[o] * inv;
        }
    }
}

// ---------------- host launcher ----------------
extern "C" void kernel_launch(void* const* d_in, const int* in_sizes, int n_in,
                              void* d_out, int out_size, void* d_ws, size_t ws_size,
                              hipStream_t stream)
{
    (void)in_sizes; (void)n_in; (void)out_size; (void)d_ws; (void)ws_size;
    const int* x = (const int*)d_in[0];
    const float* emb   = (const float*)d_in[1];
    const float* Wih_f = (const float*)d_in[2];
    const float* Whh_f = (const float*)d_in[3];
    const float* bf    = (const float*)d_in[4];
    const float* Wih_b = (const float*)d_in[5];
    const float* Whh_b = (const float*)d_in[6];
    const float* bb    = (const float*)d_in[7];
    const float* Wlin  = (const float*)d_in[8];
    const float* blin  = (const float*)d_in[9];
    float* out = (float*)d_out;

    k_zero<<<128, 256, 0, stream>>>();

    void* args[] = {
        (void*)&x, (void*)&emb,
        (void*)&Wih_f, (void*)&Whh_f, (void*)&bf,
        (void*)&Wih_b, (void*)&Whh_b, (void*)&bb
    };
    hipLaunchCooperativeKernel((const void*)k_lstm, dim3(NBLK), dim3(NTHR), args, 0, stream);

    k_out<<<1024, 256, 0, stream>>>(Wlin, blin, out);
}

// Round 11
// 2030.640 us; speedup vs baseline: 1.1678x; 1.1678x over previous
//
#include <hip/hip_runtime.h>
#include <stdint.h>

// Problem dims
#define Tn 512
#define Bn 128
#define NTOK (Bn*Tn)     // 65536
#define En 300
#define Hn 300
#define On 9
#define LDK 328          // LDS row stride in shorts (656 B rows, 16B-aligned)
#define HS 60            // hidden units per slice
#define NSL 5            // slices per direction (5*60 = 300)
#define NCH 8            // batch chunks
#define MC 16            // batch rows per chunk (one m-tile)
#define GLD 244          // padded Gsm row stride (floats): 4*240%32==0 was a 4-way write conflict
#define NBLK (2*NCH*NSL) // 80 blocks
#define NTHR 960         // 15 waves = 1 m-tile x 15 n-tiles; == MC*HS cell threads

#define HXW 304          // g_hx row stride in dwords (one tagged packet per hidden unit)
#define HXSLOT (Bn*HXW)  // dwords per parity slot
#define HXDIR (2*HXSLOT) // dwords per direction (2 parity slots)

typedef short s4v __attribute__((ext_vector_type(4)));
typedef short s8v __attribute__((ext_vector_type(8)));
typedef float f4v __attribute__((ext_vector_type(4)));

// ---- static device scratch (d_ws unused) ----
__device__ unsigned short g_hcat[NTOK * 2 * Hn];   // 78,643,200 B — h outputs
// Tagged h-exchange packets: dword = (bf16(h) << 16) | produced_step.
// The data IS the flag: one atomic dword store publishes value+validity.
// Layout lessons (R8-R10, all regressed): keep DWORD granularity (qword
// atomics write-amplify), keep [row][unit] layout + the tid->(ebl,ejj) cell
// mapping (any mapping whose wave-publishes scatter across 64B lines costs
// ~250 MB write amplification + extra poll retries at the coherence point).
__device__ unsigned int   g_hx[2 * HXDIR];         // 622,592 B

__device__ inline float b2f(unsigned short u){ unsigned v = ((unsigned)u) << 16; float f; __builtin_memcpy(&f, &v, 4); return f; }
__device__ inline unsigned short f2b(float f){ unsigned u; __builtin_memcpy(&u, &f, 4); u = u + 0x7fffu + ((u >> 16) & 1u); return (unsigned short)(u >> 16); }
__device__ inline float sigf(float x){ return 1.f / (1.f + __expf(-x)); }
__device__ inline float tanh_f(float x){ return 2.f / (1.f + __expf(-2.f * x)) - 1.f; }

// LDS-only barrier: drains lgkmcnt but NOT vmcnt, so in-flight global stores
// (the fire-and-forget h/hcat publishes) never sit on the critical path.
__device__ inline void bar_lgkm(){ asm volatile("s_waitcnt lgkmcnt(0)\n\ts_barrier" ::: "memory"); }

// ---------------- K0: init h-exchange tags to 0xFFFF (never matches a real step) ----------------
__global__ __launch_bounds__(256) void k_zero()
{
    const int i = blockIdx.x * 256 + threadIdx.x;
    const int stride = gridDim.x * 256;
    for (int j = i; j < 2 * HXDIR; j += stride) g_hx[j] = 0xFFFFu;
}

// ---------------- K1: fused bidirectional LSTM recurrence ----------------
// R11 = exact restore of the best harness-verified configuration (R4,
// k_lstm 1890 us / total 2032 us). Structure:
//  - MFMA1 from Aemb (compute during the peers' publish window)
//  - P3 poll: 4 unconditional dword atomic loads, straight-line, batched
//    behind one waitcnt; reload-all retry (parity-slot induction safe)
//  - emb prefetch AFTER the poll (never ahead of polls in the in-order
//    vmcnt retire queue; token ids from LDS)
//  - MFMA2 from Hb after an LDS-only barrier
//  - Gsm gate dump (re-coalesces gates -> cell mapping so publishes are
//    line-contiguous) -> cell -> publish hx (atomic) -> hcat (atomic)
//  - Aemb writeback, LDS-only barrier
// Retired arcs (all regressed or hung): XCD co-location (R2/R3 hangs),
// pre-MFMA atomic probe (R5: atomics fence LDS reads), dual-stream (R6:
// reg spill + barrier cost), in-wave transpose (R8-R10: publish scatter).
__global__ __launch_bounds__(NTHR, 4) void k_lstm(
    const int* __restrict__ x, const float* __restrict__ emb,
    const float* __restrict__ W_ih_f, const float* __restrict__ W_hh_f, const float* __restrict__ b_f,
    const float* __restrict__ W_ih_b, const float* __restrict__ W_hh_b, const float* __restrict__ b_b)
{
    const int bi    = blockIdx.x;
    const int dir   = bi / (NCH * NSL);
    const int rem   = bi % (NCH * NSL);
    const int chunk = rem / NSL;
    const int slice = rem % NSL;
    const int j0    = slice * HS;
    const int b0    = chunk * MC;

    const float* Wih  = dir ? W_ih_b : W_ih_f;
    const float* Whh  = dir ? W_hh_b : W_hh_f;
    const float* bias = dir ? b_b    : b_f;
    unsigned int* hxd = g_hx + dir * HXDIR;

    __shared__ __align__(16) unsigned short Aemb[2][MC * LDK]; // 21 KB emb staging, double-buffered
    __shared__ __align__(16) unsigned short Hb[MC * LDK];      // 10.5 KB h staging
    __shared__ __align__(16) float Gsm[MC * GLD];              // 15.6 KB gate dump (padded stride)
    __shared__ int Xl[MC * Tn];                                // 32 KB token ids (kills x-load from pf chain)

    const int tid  = threadIdx.x;
    const int lane = tid & 63;
    const int wid  = tid >> 6;              // 15 waves
    const int n0   = wid * 16;              // 15 n-tiles (240 gate cols); single m-tile
    const int kq   = (lane >> 4) * 8;       // k-subgroup within 32

    // ---- preload weight B-fragments (fp32 -> bf16 once, weight-stationary) ----
    // local gate col layout: [i(60) | f(60) | g(60) | o(60)]
    const int nloc = n0 + (lane & 15);      // 0..239
    const int q    = nloc / HS;             // gate index 0..3
    const int jjn  = nloc % HS;
    const int grow = q * Hn + j0 + jjn;     // global row in [1200]
    s8v bih[10], bhh[10];
#pragma unroll
    for (int kc = 0; kc < 10; kc++) {
        int kb = kc * 32 + kq;
        s8v fi = {0,0,0,0,0,0,0,0}, fh = {0,0,0,0,0,0,0,0};
#pragma unroll
        for (int j = 0; j < 8; j++) {
            int k = kb + j;
            if (k < En) {
                fi[j] = (short)f2b(Wih[grow * En + k]);
                fh[j] = (short)f2b(Whh[grow * Hn + k]);
            }
        }
        bih[kc] = fi; bhh[kc] = fh;
    }

    // ---- per-thread cell state: tid <-> (batch row ebl, unit ejj); NTHR == MC*HS ----
    const int ebl = tid / HS;   // 0..15
    const int ejj = tid % HS;   // 0..59
    const float bi_i = bias[0 * Hn + j0 + ejj];
    const float bi_f = bias[1 * Hn + j0 + ejj];
    const float bi_g = bias[2 * Hn + j0 + ejj];
    const float bi_o = bias[3 * Hn + j0 + ejj];
    float creg = 0.f;
    const bool pub = ((ejj & 1) == 0);      // even-ejj lanes store packed hcat dwords

    // ---- P3 assignment: 4 packets per thread over the OTHER 4 slices ----
    // (MC * 4*HS == 4*NTHR exactly; own slice [j0,j0+60) comes via LDS self-write)
    int goffA[4], loffA[4];
#pragma unroll
    for (int j = 0; j < 4; j++) {
        int i  = tid + j * NTHR;            // 0..3839
        int r  = i / (4 * HS);              // row 0..15
        int c2 = i - r * (4 * HS);          // 0..239
        int c  = (c2 < j0) ? c2 : (c2 + HS);// skip own slice's 60 columns
        goffA[j] = (b0 + r) * HXW + c;
        loffA[j] = r * LDK + c;
    }

    // ---- prologue: stage emb(s=0) into Aemb[0]; stage token ids; zero Hb pad ----
    {
        const int t0 = dir ? (Tn - 1) : 0;
        for (int i = tid; i < MC * 80; i += NTHR) {
            int r = i / 80, c = i - r * 80;
            s4v v = {0, 0, 0, 0};
            if (c < 75) {
                int xi = x[(b0 + r) * Tn + t0];
                float4 f = *(const float4*)(emb + (size_t)xi * En + c * 4);
                v[0] = (short)f2b(f.x); v[1] = (short)f2b(f.y);
                v[2] = (short)f2b(f.z); v[3] = (short)f2b(f.w);
            }
            *(s4v*)&Aemb[0][r * LDK + c * 4] = v;
        }
        for (int i = tid; i < MC * Tn; i += NTHR) {
            int r = i >> 9, tt = i & (Tn - 1);
            Xl[i] = x[(b0 + r) * Tn + tt];          // Xl[r*512 + t]
        }
        // MFMA2 reads shorts [0,320) per row; only [0,300) is ever filled. Zero
        // the pad once (garbage could be NaN; NaN*0 = NaN poisons the MFMA).
        if (tid < MC * 20) {
            int r = tid / 20, c = 300 + (tid % 20);
            Hb[r * LDK + c] = 0;
        }
        __syncthreads();
    }

#pragma unroll 1
    for (int s = 0; s < Tn; s++) {
        const int t   = dir ? (Tn - 1 - s) : s;
        const int cur = s & 1, nxt = cur ^ 1;

        // MFMA1: input projection part from Aemb[cur] (runs during the wait window)
        f4v acc = {0.f, 0.f, 0.f, 0.f};
        {
            const unsigned short* abase = &Aemb[cur][(lane & 15) * LDK + kq];
#pragma unroll
            for (int kc = 0; kc < 10; kc++) {
                s8v a = *(const s8v*)(abase + kc * 32);
                acc = __builtin_amdgcn_mfma_f32_16x16x32_bf16(a, bih[kc], acc, 0, 0, 0);
            }
        }

        if (s) {
            // P3: poll tagged packets of the other 4 slices. Unconditional
            // straight-line loads -> compiler batches all 4 issues behind one
            // waitcnt; a retry round costs ~1 MALL latency, not 4.
            // Reload-all retry is safe: a satisfied packet cannot change until
            // WE publish step s (peers are blocked in their own step-s+1 poll).
            const unsigned tgt = (unsigned)(s - 1);
            const unsigned int* hsrc = hxd + (s & 1) * HXSLOT;
            unsigned int pv0, pv1, pv2, pv3;
            for (;;) {
                pv0 = __hip_atomic_load(hsrc + goffA[0], __ATOMIC_RELAXED, __HIP_MEMORY_SCOPE_AGENT);
                pv1 = __hip_atomic_load(hsrc + goffA[1], __ATOMIC_RELAXED, __HIP_MEMORY_SCOPE_AGENT);
                pv2 = __hip_atomic_load(hsrc + goffA[2], __ATOMIC_RELAXED, __HIP_MEMORY_SCOPE_AGENT);
                pv3 = __hip_atomic_load(hsrc + goffA[3], __ATOMIC_RELAXED, __HIP_MEMORY_SCOPE_AGENT);
                unsigned bad = ((pv0 ^ tgt) | (pv1 ^ tgt) | (pv2 ^ tgt) | (pv3 ^ tgt)) & 0xffffu;
                if (!bad) break;
            }
            Hb[loffA[0]] = (unsigned short)(pv0 >> 16);
            Hb[loffA[1]] = (unsigned short)(pv1 >> 16);
            Hb[loffA[2]] = (unsigned short)(pv2 >> 16);
            Hb[loffA[3]] = (unsigned short)(pv3 >> 16);
        }

        // emb prefetch for s+1, issued AFTER the poll: its ~900cy HBM latency
        // (token id from LDS, not a dependent global load) hides under
        // MFMA2 + dump + cell before the writeback consumes it — and it
        // never sits ahead of poll loads in the in-order vmcnt queue.
        float4 pf[2];
        const bool do_pf = (s + 1 < Tn);
        if (do_pf) {
            const int tn1 = dir ? (Tn - 2 - s) : (s + 1);
#pragma unroll
            for (int k = 0; k < 2; k++) {
                int i = tid + k * NTHR;            // < 1920; valid when < 1280 = MC*80
                if (i < MC * 80) {
                    int r = i / 80, c = i - r * 80;
                    if (c < 75) {
                        int xi = Xl[(r << 9) + tn1];
                        pf[k] = *(const float4*)(emb + (size_t)xi * En + c * 4);
                    }
                }
            }
        }

        if (s) {
            bar_lgkm();   // bar B: Hb ready (LDS only — no vmcnt drain)

            // MFMA2: recurrent part from Hb
            const unsigned short* abase = &Hb[(lane & 15) * LDK + kq];
#pragma unroll
            for (int kc = 0; kc < 10; kc++) {
                s8v a = *(const s8v*)(abase + kc * 32);
                acc = __builtin_amdgcn_mfma_f32_16x16x32_bf16(a, bhh[kc], acc, 0, 0, 0);
            }
        }
        // s == 0: h_0 == 0, recurrent term is zero — skip P3/MFMA2 entirely.

        // dump gates (C layout: col=lane&15, row=(lane>>4)*4+reg; single m-tile)
        {
            int col   = n0 + (lane & 15);
            int rbase = (lane >> 4) * 4;
#pragma unroll
            for (int r2 = 0; r2 < 4; r2++) Gsm[(rbase + r2) * GLD + col] = acc[r2];
        }
        bar_lgkm();   // bar C: Gsm ready

        // elementwise LSTM cell + publishes
        {
            float gi  = Gsm[ebl * GLD + 0 * HS + ejj] + bi_i;
            float gf  = Gsm[ebl * GLD + 1 * HS + ejj] + bi_f;
            float gg2 = Gsm[ebl * GLD + 2 * HS + ejj] + bi_g;
            float go  = Gsm[ebl * GLD + 3 * HS + ejj] + bi_o;
            float iv = sigf(gi), fv = sigf(gf), gv = tanh_f(gg2), ov = sigf(go);
            creg = fv * creg + iv * gv;
            float h = ov * tanh_f(creg);
            unsigned hb16 = (unsigned)f2b(h);

            // own-slice h for step s+1 goes through LDS (safe: MFMA2(s) reads of
            // Hb completed before bar C; bar D orders this write for s+1)
            Hb[ebl * LDK + j0 + ejj] = (unsigned short)hb16;

            // tagged packet for the other 4 slices (fire-and-forget, agent scope)
            __hip_atomic_store(hxd + ((s + 1) & 1) * HXSLOT + (b0 + ebl) * HXW + (j0 + ejj),
                               (hb16 << 16) | (unsigned)s,
                               __ATOMIC_RELAXED, __HIP_MEMORY_SCOPE_AGENT);

            float hn = __shfl_down(h, 1);          // partner (ejj+1) in same wave
            if (pub) {
                unsigned pkt = hb16 | ((unsigned)f2b(hn) << 16);
                __hip_atomic_store((unsigned int*)g_hcat
                                       + (((size_t)((b0 + ebl) * Tn + t)) * (2 * Hn) + dir * Hn + j0 + ejj) / 2,
                                   pkt, __ATOMIC_RELAXED, __HIP_MEMORY_SCOPE_AGENT);
            }
        }

        // writeback prefetched emb(s+1) -> Aemb[nxt] (covered by bar D)
        if (do_pf) {
#pragma unroll
            for (int k = 0; k < 2; k++) {
                int i = tid + k * NTHR;
                if (i < MC * 80) {
                    int r = i / 80, c = i - r * 80;
                    s4v v = {0, 0, 0, 0};
                    if (c < 75) {
                        v[0] = (short)f2b(pf[k].x); v[1] = (short)f2b(pf[k].y);
                        v[2] = (short)f2b(pf[k].z); v[3] = (short)f2b(pf[k].w);
                    }
                    *(s4v*)&Aemb[nxt][r * LDK + c * 4] = v;
                }
            }
        }
        bar_lgkm();   // bar D: Aemb[nxt] + Hb self-write visible (LDS only)
    }
}

// ---------------- K2: fused out-projection + softmax, one wave per 16 positions ----------------
__global__ __launch_bounds__(256) void k_out(
    const float* __restrict__ W_lin, const float* __restrict__ b_lin, float* __restrict__ out)
{
    __shared__ float Wl[On * 2 * Hn];  // 21.6 KB
    __shared__ float bl[On];
    const int tid = threadIdx.x;
    for (int i = tid; i < On * 2 * Hn; i += 256) Wl[i] = W_lin[i];
    if (tid < On) bl[tid] = b_lin[tid];
    __syncthreads();

    const int lane = tid & 63;
    const int w    = tid >> 6;
    const int wg   = blockIdx.x * 4 + w;      // 4096 waves
    for (int it = 0; it < 16; it++) {
        const int p = wg * 16 + it;           // 0..65535
        const unsigned short* row = g_hcat + (size_t)p * (2 * Hn);
        float part[On];
#pragma unroll
        for (int o = 0; o < On; o++) part[o] = 0.f;
        for (int c = 0; c < 10; c++) {
            int k = lane + 64 * c;
            if (k < 2 * Hn) {
                float v = b2f(row[k]);
#pragma unroll
                for (int o = 0; o < On; o++) part[o] += v * Wl[o * (2 * Hn) + k];
            }
        }
#pragma unroll
        for (int off = 32; off >= 1; off >>= 1) {
#pragma unroll
            for (int o = 0; o < On; o++) part[o] += __shfl_xor(part[o], off, 64);
        }
        if (lane == 0) {
            float lg[On];
            float m = -1e30f;
#pragma unroll
            for (int o = 0; o < On; o++) { lg[o] = part[o] + bl[o]; m = fmaxf(m, lg[o]); }
            float ssum = 0.f;
#pragma unroll
            for (int o = 0; o < On; o++) { lg[o] = __expf(lg[o] - m); ssum += lg[o]; }
            float inv = 1.f / ssum;
#pragma unroll
            for (int o = 0; o < On; o++) out[(size_t)p * On + o] = lg[o] * inv;
        }
    }
}

// ---------------- host launcher ----------------
extern "C" void kernel_launch(void* const* d_in, const int* in_sizes, int n_in,
                              void* d_out, int out_size, void* d_ws, size_t ws_size,
                              hipStream_t stream)
{
    (void)in_sizes; (void)n_in; (void)out_size; (void)d_ws; (void)ws_size;
    const int* x = (const int*)d_in[0];
    const float* emb   = (const float*)d_in[1];
    const float* Wih_f = (const float*)d_in[2];
    const float* Whh_f = (const float*)d_in[3];
    const float* bf    = (const float*)d_in[4];
    const float* Wih_b = (const float*)d_in[5];
    const float* Whh_b = (const float*)d_in[6];
    const float* bb    = (const float*)d_in[7];
    const float* Wlin  = (const float*)d_in[8];
    const float* blin  = (const float*)d_in[9];
    float* out = (float*)d_out;

    k_zero<<<128, 256, 0, stream>>>();

    void* args[] = {
        (void*)&x, (void*)&emb,
        (void*)&Wih_f, (void*)&Whh_f, (void*)&bf,
        (void*)&Wih_b, (void*)&Whh_b, (void*)&bb
    };
    hipLaunchCooperativeKernel((const void*)k_lstm, dim3(NBLK), dim3(NTHR), args, 0, stream);

    k_out<<<1024, 256, 0, stream>>>(Wlin, blin, out);
}